// Round 10
// baseline (159.792 us; speedup 1.0000x reference)
//
#include <hip/hip_runtime.h>

#define D 64
#define NCLS 10
#define NG 128
#define NPW 64    // nodes per wave in k_pool
#define NBLK 128  // partition blocks for bucket build
#define MAXNB 512 // max coarse buckets (N/256)

// bf16 helpers (RNE encode, cheap decode)
__device__ __forceinline__ unsigned short f2bf(float v) {
    unsigned b = __float_as_uint(v);
    b += 0x7fff + ((b >> 16) & 1);
    return (unsigned short)(b >> 16);
}
__device__ __forceinline__ float bf2f(unsigned short h) {
    return __uint_as_float(((unsigned)h) << 16);
}

// ---- h_scaled = (x @ W1) * dinv(row) -> bf16, LDS-tiled register-blocked GEMM ----
__global__ __launch_bounds__(256) void k_xw1(const float* __restrict__ x,
                      const float* __restrict__ W1, const float* __restrict__ dinv,
                      int N, ushort4* __restrict__ hs4) {
    __shared__ float wl[D * D];   // W1[k][c]
    __shared__ float xt[64 * D];  // x-tile, row-major [r][k]
    int tid = threadIdx.x;
    const float4* W4 = (const float4*)W1;
    float4* wl4 = (float4*)wl;
#pragma unroll
    for (int i = 0; i < 4; ++i) wl4[i * 256 + tid] = W4[i * 256 + tid];
    int row0 = blockIdx.x * 64;
    const float4* x4 = (const float4*)x;
    float4* xt4 = (float4*)xt;
#pragma unroll
    for (int i = 0; i < 4; ++i) {
        int flat = i * 256 + tid;
        int row = row0 + (flat >> 4);
        float4 v = make_float4(0.f, 0.f, 0.f, 0.f);
        if (row < N) v = x4[(size_t)row * 16 + (flat & 15)];
        xt4[flat] = v;
    }
    __syncthreads();
    int col4 = tid & 15;
    int rowg = tid >> 4;
    float4 acc[4];
#pragma unroll
    for (int i = 0; i < 4; ++i) acc[i] = make_float4(0.f, 0.f, 0.f, 0.f);
#pragma unroll 8
    for (int k = 0; k < D; ++k) {
        float4 wv = *(const float4*)&wl[k * D + col4 * 4];
#pragma unroll
        for (int i = 0; i < 4; ++i) {
            float xv = xt[(rowg * 4 + i) * D + k];
            acc[i].x += xv * wv.x;
            acc[i].y += xv * wv.y;
            acc[i].z += xv * wv.z;
            acc[i].w += xv * wv.w;
        }
    }
#pragma unroll
    for (int i = 0; i < 4; ++i) {
        int row = row0 + rowg * 4 + i;
        if (row >= N) continue;
        float d = dinv[row];
        ushort4 o;
        o.x = f2bf(acc[i].x * d);
        o.y = f2bf(acc[i].y * d);
        o.z = f2bf(acc[i].z * d);
        o.w = f2bf(acc[i].w * d);
        hs4[(size_t)row * 16 + col4] = o;
    }
}

// ---- bucket build pass 1: per-block histogram of dst>>8 (+ zero gsum/gcnt) ----
__global__ __launch_bounds__(256) void k_bcount(const int* __restrict__ dst, int E,
                                                int NB, int* __restrict__ blkCount,
                                                float* __restrict__ gsum,
                                                float* __restrict__ gcnt) {
    __shared__ int cnt[MAXNB];
    int tid = threadIdx.x;
    int blk = blockIdx.x;
    int gt = blk * 256 + tid;
    if (gt < NG * D) gsum[gt] = 0.f;
    if (gt < NG) gcnt[gt] = 0.f;
    for (int b = tid; b < NB; b += 256) cnt[b] = 0;
    __syncthreads();
    int ch = (E + NBLK - 1) / NBLK;
    int beg = blk * ch, end = min(beg + ch, E);
    for (int i = beg + tid; i < end; i += 256) atomicAdd(&cnt[dst[i] >> 8], 1);
    __syncthreads();
    for (int b = tid; b < NB; b += 256) blkCount[b * NBLK + blk] = cnt[b];
}

// ---- bucket build pass 2: totals -> exclusive bases, per-(bucket,block) bases ----
__global__ __launch_bounds__(512) void k_bbase(int* __restrict__ blkCount, int NB, int E,
                                               int* __restrict__ bucketBase) {
    __shared__ int sd[512];
    int tid = threadIdx.x;
    int4 c[NBLK / 4];
    int tot = 0;
    if (tid < NB) {
        const int4* p = (const int4*)&blkCount[tid * NBLK];
#pragma unroll
        for (int j = 0; j < NBLK / 4; ++j) {
            c[j] = p[j];
            tot += c[j].x + c[j].y + c[j].z + c[j].w;
        }
    }
    sd[tid] = (tid < NB) ? tot : 0;
    __syncthreads();
    for (int off = 1; off < 512; off <<= 1) {
        int tmp = (tid >= off) ? sd[tid - off] : 0;
        __syncthreads();
        sd[tid] += tmp;
        __syncthreads();
    }
    if (tid < NB) {
        int run = (tid == 0) ? 0 : sd[tid - 1];
        bucketBase[tid] = run;
        int4* p = (int4*)&blkCount[tid * NBLK];
#pragma unroll
        for (int j = 0; j < NBLK / 4; ++j) {
            int t0 = c[j].x; c[j].x = run; run += t0;
            int t1 = c[j].y; c[j].y = run; run += t1;
            int t2 = c[j].z; c[j].z = run; run += t2;
            int t3 = c[j].w; c[j].w = run; run += t3;
            p[j] = c[j];
        }
    }
    if (tid == 0) bucketBase[NB] = E;
}

// ---- bucket build pass 3: place packed (src<<8)|dstLocal grouped by bucket ----
__global__ __launch_bounds__(256) void k_bplace(const int* __restrict__ src,
                                                const int* __restrict__ dst, int E,
                                                int NB, const int* __restrict__ blkCount,
                                                int* __restrict__ e2p) {
    __shared__ int cur[MAXNB];
    int tid = threadIdx.x;
    int blk = blockIdx.x;
    for (int b = tid; b < NB; b += 256) cur[b] = blkCount[b * NBLK + blk];
    __syncthreads();
    int ch = (E + NBLK - 1) / NBLK;
    int beg = blk * ch, end = min(beg + ch, E);
    for (int i = beg + tid; i < end; i += 256) {
        int s = src[i], t = dst[i];
        int pos = atomicAdd(&cur[t >> 8], 1);
        e2p[pos] = (s << 8) | (t & 255);
    }
}

// ---- fused CSR finalize: per-bucket histogram+scan -> rowptr & dinv, scatter srcs ----
__global__ __launch_bounds__(256) void k_csrdeg(const int* __restrict__ e2p,
                                                const int* __restrict__ bucketBase,
                                                int N, int E,
                                                int* __restrict__ rowptr,
                                                float* __restrict__ dinv,
                                                int* __restrict__ srcs) {
    __shared__ int cnt[256];
    __shared__ int sd[256];
    __shared__ int cur[256];
    int tid = threadIdx.x;
    int node0 = blockIdx.x << 8;
    int bb = bucketBase[blockIdx.x];
    int end = bucketBase[blockIdx.x + 1];
    cnt[tid] = 0;
    __syncthreads();
    for (int i = bb + tid; i < end; i += 256) atomicAdd(&cnt[e2p[i] & 255], 1);
    __syncthreads();
    sd[tid] = cnt[tid];
    __syncthreads();
    for (int off = 1; off < 256; off <<= 1) {
        int tmp = (tid >= off) ? sd[tid - off] : 0;
        __syncthreads();
        sd[tid] += tmp;
        __syncthreads();
    }
    int excl = (tid == 0) ? 0 : sd[tid - 1];
    int node = node0 + tid;
    if (node < N) {
        rowptr[node] = bb + excl;
        dinv[node] = rsqrtf((float)(cnt[tid] + 1));
    }
    cur[tid] = bb + excl;
    if (blockIdx.x == 0 && tid == 0) rowptr[N] = E;
    __syncthreads();
    for (int i = bb + tid; i < end; i += 256) {
        int p = e2p[i];
        int pos = atomicAdd(&cur[p & 255], 1);
        srcs[pos] = p >> 8;
    }
}

// ---- gather-aggregate: wave per dst node; sub-group-stride edges ----
// NT hints on srcs reads and r4 writes so the hs4 gather table keeps the L2.
__global__ void k_gather(const ushort4* __restrict__ hs4, const float* __restrict__ dinv,
                         const int* __restrict__ rowptr, const int* __restrict__ srcs,
                         const float* __restrict__ b1, int N,
                         unsigned long long* __restrict__ r4) {
    int node = (blockIdx.x * blockDim.x + threadIdx.x) >> 6;
    int lane = threadIdx.x & 63;
    if (node >= N) return;
    int begin = rowptr[node];
    int end = rowptr[node + 1];
    int c4 = lane & 15;
    int sub = lane >> 4;
    float4 sum = make_float4(0.f, 0.f, 0.f, 0.f);
    if (sub == 0) {  // self-loop (already *dinv[node])
        ushort4 u = hs4[(size_t)node * 16 + c4];
        sum.x = bf2f(u.x); sum.y = bf2f(u.y); sum.z = bf2f(u.z); sum.w = bf2f(u.w);
    }
    int k = begin + sub;
    for (; k + 4 < end; k += 8) {  // two independent gathers in flight
        int s0 = __builtin_nontemporal_load(&srcs[k]);
        int s1 = __builtin_nontemporal_load(&srcs[k + 4]);
        ushort4 u0 = hs4[(size_t)s0 * 16 + c4];
        ushort4 u1 = hs4[(size_t)s1 * 16 + c4];
        sum.x += bf2f(u0.x) + bf2f(u1.x);
        sum.y += bf2f(u0.y) + bf2f(u1.y);
        sum.z += bf2f(u0.z) + bf2f(u1.z);
        sum.w += bf2f(u0.w) + bf2f(u1.w);
    }
    if (k < end) {
        int s = __builtin_nontemporal_load(&srcs[k]);
        ushort4 u = hs4[(size_t)s * 16 + c4];
        sum.x += bf2f(u.x); sum.y += bf2f(u.y);
        sum.z += bf2f(u.z); sum.w += bf2f(u.w);
    }
    sum.x += __shfl_xor(sum.x, 16); sum.y += __shfl_xor(sum.y, 16);
    sum.z += __shfl_xor(sum.z, 16); sum.w += __shfl_xor(sum.w, 16);
    sum.x += __shfl_xor(sum.x, 32); sum.y += __shfl_xor(sum.y, 32);
    sum.z += __shfl_xor(sum.z, 32); sum.w += __shfl_xor(sum.w, 32);
    if (sub == 0) {
        float d = dinv[node];
        float4 b = ((const float4*)b1)[c4];
        unsigned long long ox = f2bf(fmaxf(sum.x * d + b.x, 0.f));
        unsigned long long oy = f2bf(fmaxf(sum.y * d + b.y, 0.f));
        unsigned long long oz = f2bf(fmaxf(sum.z * d + b.z, 0.f));
        unsigned long long ow = f2bf(fmaxf(sum.w * d + b.w, 0.f));
        unsigned long long pk = ox | (oy << 16) | (oz << 32) | (ow << 48);
        __builtin_nontemporal_store(pk, &r4[(size_t)node * 16 + c4]);
    }
}

// ---- mean-pool: sorted-batch run accumulation (bf16 in via NT, fp32 accum) ----
__global__ void k_pool(const unsigned long long* __restrict__ r4,
                       const int* __restrict__ batch,
                       int N, float* __restrict__ gsum, float* __restrict__ gcnt) {
    int wid = (blockIdx.x * blockDim.x + threadIdx.x) >> 6;
    int lane = threadIdx.x & 63;
    int sub = lane >> 4;
    int c4  = lane & 15;
    int start = wid * NPW;
    if (start >= N) return;
    int end = min(start + NPW, N);
    float4 sum = make_float4(0.f, 0.f, 0.f, 0.f);
    float cnt = 0.f;
    int cur_g = -1;
    for (int i = start + sub; i < end; i += 4) {
        int g = batch[i];
        if (g != cur_g) {
            if (cur_g >= 0) {
                float* gs = &gsum[cur_g * D + c4 * 4];
                atomicAdd(gs + 0, sum.x);
                atomicAdd(gs + 1, sum.y);
                atomicAdd(gs + 2, sum.z);
                atomicAdd(gs + 3, sum.w);
                if (c4 == 0) atomicAdd(&gcnt[cur_g], cnt);
            }
            sum = make_float4(0.f, 0.f, 0.f, 0.f);
            cnt = 0.f;
            cur_g = g;
        }
        unsigned long long pk = __builtin_nontemporal_load(&r4[(size_t)i * 16 + c4]);
        unsigned lo = (unsigned)pk;
        unsigned hi = (unsigned)(pk >> 32);
        sum.x += __uint_as_float(lo << 16);
        sum.y += __uint_as_float(lo & 0xffff0000u);
        sum.z += __uint_as_float(hi << 16);
        sum.w += __uint_as_float(hi & 0xffff0000u);
        cnt += 1.f;
    }
    if (cur_g >= 0) {
        float* gs = &gsum[cur_g * D + c4 * 4];
        atomicAdd(gs + 0, sum.x);
        atomicAdd(gs + 1, sum.y);
        atomicAdd(gs + 2, sum.z);
        atomicAdd(gs + 3, sum.w);
        if (c4 == 0) atomicAdd(&gcnt[cur_g], cnt);
    }
}

// ---- head ----
__global__ void k_head(const float* __restrict__ gsum, const float* __restrict__ gcnt,
                       const float* __restrict__ W2, const float* __restrict__ b2,
                       float* __restrict__ out) {
    int g = threadIdx.x;
    if (g >= NG) return;
    float cnt = gcnt[g];
    cnt = cnt > 1.f ? cnt : 1.f;
    float inv = 1.f / cnt;
    float logits[NCLS];
#pragma unroll
    for (int c = 0; c < NCLS; ++c) logits[c] = b2[c];
    for (int k = 0; k < D; ++k) {
        float hk = gsum[g * D + k] * inv;
#pragma unroll
        for (int c = 0; c < NCLS; ++c) logits[c] += hk * W2[k * NCLS + c];
    }
    float m = logits[0];
#pragma unroll
    for (int c = 1; c < NCLS; ++c) m = fmaxf(m, logits[c]);
    float se = 0.f;
#pragma unroll
    for (int c = 0; c < NCLS; ++c) se += expf(logits[c] - m);
    float lse = m + logf(se);
#pragma unroll
    for (int c = 0; c < NCLS; ++c) out[g * NCLS + c] = logits[c] - lse;
}

static inline size_t pad256(size_t x) { return (x + 255) & ~(size_t)255; }

extern "C" void kernel_launch(void* const* d_in, const int* in_sizes, int n_in,
                              void* d_out, int out_size, void* d_ws, size_t ws_size,
                              hipStream_t stream) {
    const float* x     = (const float*)d_in[0];
    const int*   ei    = (const int*)d_in[1];   // [2, E]: src row then dst row
    const int*   batch = (const int*)d_in[2];
    const float* W1    = (const float*)d_in[3];
    const float* b1    = (const float*)d_in[4];
    const float* W2    = (const float*)d_in[5];
    const float* b2    = (const float*)d_in[6];
    float* out = (float*)d_out;

    const int N = in_sizes[0] / D;   // 100000
    const int E = in_sizes[1] / 2;   // 1000000
    const int NB = (N + 255) >> 8;   // 391 coarse buckets

    char* w = (char*)d_ws;
    ushort4* hs4      = (ushort4*)w; w += pad256((size_t)N * D * 2);
    unsigned long long* r4 = (unsigned long long*)w; w += pad256((size_t)N * D * 2);
    float* dinv       = (float*)w;  w += pad256((size_t)N * 4);
    int*   rowptr     = (int*)w;    w += pad256((size_t)(N + 1) * 4);
    int*   srcs       = (int*)w;    w += pad256((size_t)E * 4);
    int*   e2p        = (int*)w;    w += pad256((size_t)E * 4);
    int*   blkCount   = (int*)w;    w += pad256((size_t)MAXNB * NBLK * 4);
    int*   bucketBase = (int*)w;    w += pad256((size_t)(MAXNB + 1) * 4);
    float* gsum       = (float*)w;  w += pad256((size_t)NG * D * 4);
    float* gcnt       = (float*)w;  w += pad256((size_t)NG * 4);

    const int* e_src = ei;
    const int* e_dst = ei + E;

    k_bcount<<<NBLK, 256, 0, stream>>>(e_dst, E, NB, blkCount, gsum, gcnt);
    k_bbase<<<1, 512, 0, stream>>>(blkCount, NB, E, bucketBase);
    k_bplace<<<NBLK, 256, 0, stream>>>(e_src, e_dst, E, NB, blkCount, e2p);
    k_csrdeg<<<NB, 256, 0, stream>>>(e2p, bucketBase, N, E, rowptr, dinv, srcs);

    k_xw1<<<(N + 63) / 64, 256, 0, stream>>>(x, W1, dinv, N, hs4);

    {
        long long threads = (long long)N * 64;
        int blocks = (int)((threads + 255) / 256);
        k_gather<<<blocks, 256, 0, stream>>>(hs4, dinv, rowptr, srcs, b1, N, r4);
    }
    {
        int waves = (N + NPW - 1) / NPW;
        long long threads = (long long)waves * 64;
        int blocks = (int)((threads + 255) / 256);
        k_pool<<<blocks, 256, 0, stream>>>(r4, batch, N, gsum, gcnt);
    }
    k_head<<<1, 128, 0, stream>>>(gsum, gcnt, W2, b2, out);
}

// Round 11
// 146.651 us; speedup vs baseline: 1.0896x; 1.0896x over previous
//
#include <hip/hip_runtime.h>

#define D 64
#define NCLS 10
#define NG 128
#define NPW 64    // nodes per wave in k_pool
#define NBLK 128  // partition blocks for bucket build
#define MAXNB 512 // max coarse buckets (N/256)

// bf16 helpers (RNE encode, cheap decode)
__device__ __forceinline__ unsigned short f2bf(float v) {
    unsigned b = __float_as_uint(v);
    b += 0x7fff + ((b >> 16) & 1);
    return (unsigned short)(b >> 16);
}
__device__ __forceinline__ float bf2f(unsigned short h) {
    return __uint_as_float(((unsigned)h) << 16);
}

// ---- h_scaled = (x @ W1) * dinv(row) -> bf16, LDS-tiled register-blocked GEMM ----
__global__ __launch_bounds__(256) void k_xw1(const float* __restrict__ x,
                      const float* __restrict__ W1, const float* __restrict__ dinv,
                      int N, ushort4* __restrict__ hs4) {
    __shared__ float wl[D * D];   // W1[k][c]
    __shared__ float xt[64 * D];  // x-tile, row-major [r][k]
    int tid = threadIdx.x;
    const float4* W4 = (const float4*)W1;
    float4* wl4 = (float4*)wl;
#pragma unroll
    for (int i = 0; i < 4; ++i) wl4[i * 256 + tid] = W4[i * 256 + tid];
    int row0 = blockIdx.x * 64;
    const float4* x4 = (const float4*)x;
    float4* xt4 = (float4*)xt;
#pragma unroll
    for (int i = 0; i < 4; ++i) {
        int flat = i * 256 + tid;
        int row = row0 + (flat >> 4);
        float4 v = make_float4(0.f, 0.f, 0.f, 0.f);
        if (row < N) v = x4[(size_t)row * 16 + (flat & 15)];
        xt4[flat] = v;
    }
    __syncthreads();
    int col4 = tid & 15;
    int rowg = tid >> 4;
    float4 acc[4];
#pragma unroll
    for (int i = 0; i < 4; ++i) acc[i] = make_float4(0.f, 0.f, 0.f, 0.f);
#pragma unroll 8
    for (int k = 0; k < D; ++k) {
        float4 wv = *(const float4*)&wl[k * D + col4 * 4];
#pragma unroll
        for (int i = 0; i < 4; ++i) {
            float xv = xt[(rowg * 4 + i) * D + k];
            acc[i].x += xv * wv.x;
            acc[i].y += xv * wv.y;
            acc[i].z += xv * wv.z;
            acc[i].w += xv * wv.w;
        }
    }
#pragma unroll
    for (int i = 0; i < 4; ++i) {
        int row = row0 + rowg * 4 + i;
        if (row >= N) continue;
        float d = dinv[row];
        ushort4 o;
        o.x = f2bf(acc[i].x * d);
        o.y = f2bf(acc[i].y * d);
        o.z = f2bf(acc[i].z * d);
        o.w = f2bf(acc[i].w * d);
        hs4[(size_t)row * 16 + col4] = o;
    }
}

// ---- bucket build pass 1: per-block histogram of dst>>8 (+ zero gsum/gcnt) ----
__global__ __launch_bounds__(256) void k_bcount(const int* __restrict__ dst, int E,
                                                int NB, int* __restrict__ blkCount,
                                                float* __restrict__ gsum,
                                                float* __restrict__ gcnt) {
    __shared__ int cnt[MAXNB];
    int tid = threadIdx.x;
    int blk = blockIdx.x;
    int gt = blk * 256 + tid;
    if (gt < NG * D) gsum[gt] = 0.f;
    if (gt < NG) gcnt[gt] = 0.f;
    for (int b = tid; b < NB; b += 256) cnt[b] = 0;
    __syncthreads();
    int ch = (E + NBLK - 1) / NBLK;
    int beg = blk * ch, end = min(beg + ch, E);
    for (int i = beg + tid; i < end; i += 256) atomicAdd(&cnt[dst[i] >> 8], 1);
    __syncthreads();
    for (int b = tid; b < NB; b += 256) blkCount[b * NBLK + blk] = cnt[b];
}

// ---- bucket build pass 2: totals -> exclusive bases, per-(bucket,block) bases ----
__global__ __launch_bounds__(512) void k_bbase(int* __restrict__ blkCount, int NB, int E,
                                               int* __restrict__ bucketBase) {
    __shared__ int sd[512];
    int tid = threadIdx.x;
    int4 c[NBLK / 4];
    int tot = 0;
    if (tid < NB) {
        const int4* p = (const int4*)&blkCount[tid * NBLK];
#pragma unroll
        for (int j = 0; j < NBLK / 4; ++j) {
            c[j] = p[j];
            tot += c[j].x + c[j].y + c[j].z + c[j].w;
        }
    }
    sd[tid] = (tid < NB) ? tot : 0;
    __syncthreads();
    for (int off = 1; off < 512; off <<= 1) {
        int tmp = (tid >= off) ? sd[tid - off] : 0;
        __syncthreads();
        sd[tid] += tmp;
        __syncthreads();
    }
    if (tid < NB) {
        int run = (tid == 0) ? 0 : sd[tid - 1];
        bucketBase[tid] = run;
        int4* p = (int4*)&blkCount[tid * NBLK];
#pragma unroll
        for (int j = 0; j < NBLK / 4; ++j) {
            int t0 = c[j].x; c[j].x = run; run += t0;
            int t1 = c[j].y; c[j].y = run; run += t1;
            int t2 = c[j].z; c[j].z = run; run += t2;
            int t3 = c[j].w; c[j].w = run; run += t3;
            p[j] = c[j];
        }
    }
    if (tid == 0) bucketBase[NB] = E;
}

// ---- bucket build pass 3: place packed (src<<8)|dstLocal grouped by bucket ----
__global__ __launch_bounds__(256) void k_bplace(const int* __restrict__ src,
                                                const int* __restrict__ dst, int E,
                                                int NB, const int* __restrict__ blkCount,
                                                int* __restrict__ e2p) {
    __shared__ int cur[MAXNB];
    int tid = threadIdx.x;
    int blk = blockIdx.x;
    for (int b = tid; b < NB; b += 256) cur[b] = blkCount[b * NBLK + blk];
    __syncthreads();
    int ch = (E + NBLK - 1) / NBLK;
    int beg = blk * ch, end = min(beg + ch, E);
    for (int i = beg + tid; i < end; i += 256) {
        int s = src[i], t = dst[i];
        int pos = atomicAdd(&cur[t >> 8], 1);
        e2p[pos] = (s << 8) | (t & 255);
    }
}

// ---- fused CSR finalize: per-bucket histogram+scan -> rowptr & dinv, scatter srcs ----
__global__ __launch_bounds__(256) void k_csrdeg(const int* __restrict__ e2p,
                                                const int* __restrict__ bucketBase,
                                                int N, int E,
                                                int* __restrict__ rowptr,
                                                float* __restrict__ dinv,
                                                int* __restrict__ srcs) {
    __shared__ int cnt[256];
    __shared__ int sd[256];
    __shared__ int cur[256];
    int tid = threadIdx.x;
    int node0 = blockIdx.x << 8;
    int bb = bucketBase[blockIdx.x];
    int end = bucketBase[blockIdx.x + 1];
    cnt[tid] = 0;
    __syncthreads();
    for (int i = bb + tid; i < end; i += 256) atomicAdd(&cnt[e2p[i] & 255], 1);
    __syncthreads();
    sd[tid] = cnt[tid];
    __syncthreads();
    for (int off = 1; off < 256; off <<= 1) {
        int tmp = (tid >= off) ? sd[tid - off] : 0;
        __syncthreads();
        sd[tid] += tmp;
        __syncthreads();
    }
    int excl = (tid == 0) ? 0 : sd[tid - 1];
    int node = node0 + tid;
    if (node < N) {
        rowptr[node] = bb + excl;
        dinv[node] = rsqrtf((float)(cnt[tid] + 1));
    }
    cur[tid] = bb + excl;
    if (blockIdx.x == 0 && tid == 0) rowptr[N] = E;
    __syncthreads();
    for (int i = bb + tid; i < end; i += 256) {
        int p = e2p[i];
        int pos = atomicAdd(&cur[p & 255], 1);
        srcs[pos] = p >> 8;
    }
}

// ---- gather-aggregate: one 16-lane group per node (4 nodes/wave) ----
// lane%16 = channel quad; each group walks its node's edges serially (2x unroll,
// 2 gathers in flight); no cross-lane reduction, no idle lanes, 4 chains/wave.
__global__ void k_gather(const ushort4* __restrict__ hs4, const float* __restrict__ dinv,
                         const int* __restrict__ rowptr, const int* __restrict__ srcs,
                         const float* __restrict__ b1, int N,
                         unsigned long long* __restrict__ r4) {
    int node = (blockIdx.x * blockDim.x + threadIdx.x) >> 4;
    int c4 = threadIdx.x & 15;
    if (node >= N) return;
    int begin = rowptr[node];
    int end = rowptr[node + 1];
    // self-loop (already *dinv[node])
    ushort4 u = hs4[(size_t)node * 16 + c4];
    float4 sum = make_float4(bf2f(u.x), bf2f(u.y), bf2f(u.z), bf2f(u.w));
    int k = begin;
    for (; k + 1 < end; k += 2) {  // two independent gathers in flight
        int s0 = srcs[k];
        int s1 = srcs[k + 1];
        ushort4 u0 = hs4[(size_t)s0 * 16 + c4];
        ushort4 u1 = hs4[(size_t)s1 * 16 + c4];
        sum.x += bf2f(u0.x) + bf2f(u1.x);
        sum.y += bf2f(u0.y) + bf2f(u1.y);
        sum.z += bf2f(u0.z) + bf2f(u1.z);
        sum.w += bf2f(u0.w) + bf2f(u1.w);
    }
    if (k < end) {
        int s = srcs[k];
        ushort4 uu = hs4[(size_t)s * 16 + c4];
        sum.x += bf2f(uu.x); sum.y += bf2f(uu.y);
        sum.z += bf2f(uu.z); sum.w += bf2f(uu.w);
    }
    float d = dinv[node];
    float4 b = ((const float4*)b1)[c4];
    unsigned long long ox = f2bf(fmaxf(sum.x * d + b.x, 0.f));
    unsigned long long oy = f2bf(fmaxf(sum.y * d + b.y, 0.f));
    unsigned long long oz = f2bf(fmaxf(sum.z * d + b.z, 0.f));
    unsigned long long ow = f2bf(fmaxf(sum.w * d + b.w, 0.f));
    r4[(size_t)node * 16 + c4] = ox | (oy << 16) | (oz << 32) | (ow << 48);
}

// ---- mean-pool: sorted-batch run accumulation (bf16 in, fp32 accum) ----
__global__ void k_pool(const unsigned long long* __restrict__ r4,
                       const int* __restrict__ batch,
                       int N, float* __restrict__ gsum, float* __restrict__ gcnt) {
    int wid = (blockIdx.x * blockDim.x + threadIdx.x) >> 6;
    int lane = threadIdx.x & 63;
    int sub = lane >> 4;
    int c4  = lane & 15;
    int start = wid * NPW;
    if (start >= N) return;
    int end = min(start + NPW, N);
    float4 sum = make_float4(0.f, 0.f, 0.f, 0.f);
    float cnt = 0.f;
    int cur_g = -1;
    for (int i = start + sub; i < end; i += 4) {
        int g = batch[i];
        if (g != cur_g) {
            if (cur_g >= 0) {
                float* gs = &gsum[cur_g * D + c4 * 4];
                atomicAdd(gs + 0, sum.x);
                atomicAdd(gs + 1, sum.y);
                atomicAdd(gs + 2, sum.z);
                atomicAdd(gs + 3, sum.w);
                if (c4 == 0) atomicAdd(&gcnt[cur_g], cnt);
            }
            sum = make_float4(0.f, 0.f, 0.f, 0.f);
            cnt = 0.f;
            cur_g = g;
        }
        unsigned long long pk = r4[(size_t)i * 16 + c4];
        unsigned lo = (unsigned)pk;
        unsigned hi = (unsigned)(pk >> 32);
        sum.x += __uint_as_float(lo << 16);
        sum.y += __uint_as_float(lo & 0xffff0000u);
        sum.z += __uint_as_float(hi << 16);
        sum.w += __uint_as_float(hi & 0xffff0000u);
        cnt += 1.f;
    }
    if (cur_g >= 0) {
        float* gs = &gsum[cur_g * D + c4 * 4];
        atomicAdd(gs + 0, sum.x);
        atomicAdd(gs + 1, sum.y);
        atomicAdd(gs + 2, sum.z);
        atomicAdd(gs + 3, sum.w);
        if (c4 == 0) atomicAdd(&gcnt[cur_g], cnt);
    }
}

// ---- head ----
__global__ void k_head(const float* __restrict__ gsum, const float* __restrict__ gcnt,
                       const float* __restrict__ W2, const float* __restrict__ b2,
                       float* __restrict__ out) {
    int g = threadIdx.x;
    if (g >= NG) return;
    float cnt = gcnt[g];
    cnt = cnt > 1.f ? cnt : 1.f;
    float inv = 1.f / cnt;
    float logits[NCLS];
#pragma unroll
    for (int c = 0; c < NCLS; ++c) logits[c] = b2[c];
    for (int k = 0; k < D; ++k) {
        float hk = gsum[g * D + k] * inv;
#pragma unroll
        for (int c = 0; c < NCLS; ++c) logits[c] += hk * W2[k * NCLS + c];
    }
    float m = logits[0];
#pragma unroll
    for (int c = 1; c < NCLS; ++c) m = fmaxf(m, logits[c]);
    float se = 0.f;
#pragma unroll
    for (int c = 0; c < NCLS; ++c) se += expf(logits[c] - m);
    float lse = m + logf(se);
#pragma unroll
    for (int c = 0; c < NCLS; ++c) out[g * NCLS + c] = logits[c] - lse;
}

static inline size_t pad256(size_t x) { return (x + 255) & ~(size_t)255; }

extern "C" void kernel_launch(void* const* d_in, const int* in_sizes, int n_in,
                              void* d_out, int out_size, void* d_ws, size_t ws_size,
                              hipStream_t stream) {
    const float* x     = (const float*)d_in[0];
    const int*   ei    = (const int*)d_in[1];   // [2, E]: src row then dst row
    const int*   batch = (const int*)d_in[2];
    const float* W1    = (const float*)d_in[3];
    const float* b1    = (const float*)d_in[4];
    const float* W2    = (const float*)d_in[5];
    const float* b2    = (const float*)d_in[6];
    float* out = (float*)d_out;

    const int N = in_sizes[0] / D;   // 100000
    const int E = in_sizes[1] / 2;   // 1000000
    const int NB = (N + 255) >> 8;   // 391 coarse buckets

    char* w = (char*)d_ws;
    ushort4* hs4      = (ushort4*)w; w += pad256((size_t)N * D * 2);
    unsigned long long* r4 = (unsigned long long*)w; w += pad256((size_t)N * D * 2);
    float* dinv       = (float*)w;  w += pad256((size_t)N * 4);
    int*   rowptr     = (int*)w;    w += pad256((size_t)(N + 1) * 4);
    int*   srcs       = (int*)w;    w += pad256((size_t)E * 4);
    int*   e2p        = (int*)w;    w += pad256((size_t)E * 4);
    int*   blkCount   = (int*)w;    w += pad256((size_t)MAXNB * NBLK * 4);
    int*   bucketBase = (int*)w;    w += pad256((size_t)(MAXNB + 1) * 4);
    float* gsum       = (float*)w;  w += pad256((size_t)NG * D * 4);
    float* gcnt       = (float*)w;  w += pad256((size_t)NG * 4);

    const int* e_src = ei;
    const int* e_dst = ei + E;

    k_bcount<<<NBLK, 256, 0, stream>>>(e_dst, E, NB, blkCount, gsum, gcnt);
    k_bbase<<<1, 512, 0, stream>>>(blkCount, NB, E, bucketBase);
    k_bplace<<<NBLK, 256, 0, stream>>>(e_src, e_dst, E, NB, blkCount, e2p);
    k_csrdeg<<<NB, 256, 0, stream>>>(e2p, bucketBase, N, E, rowptr, dinv, srcs);

    k_xw1<<<(N + 63) / 64, 256, 0, stream>>>(x, W1, dinv, N, hs4);

    {
        long long threads = (long long)N * 16;
        int blocks = (int)((threads + 255) / 256);
        k_gather<<<blocks, 256, 0, stream>>>(hs4, dinv, rowptr, srcs, b1, N, r4);
    }
    {
        int waves = (N + NPW - 1) / NPW;
        long long threads = (long long)waves * 64;
        int blocks = (int)((threads + 255) / 256);
        k_pool<<<blocks, 256, 0, stream>>>(r4, batch, N, gsum, gcnt);
    }
    k_head<<<1, 128, 0, stream>>>(gsum, gcnt, W2, b2, out);
}